// Round 1
// baseline (156.671 us; speedup 1.0000x reference)
//
#include <hip/hip_runtime.h>
#include <math.h>

#define NB   16
#define EMB  128
#define XST  20   // xsT/xaT row stride in floats: 80 B = 5*16 B -> float4-aligned rows

// One block per batch element. 256 threads = 4 waves.
// Phases:
//  A: load e1/r1/t1, rel_vec, rsim-row dot partials
//  B: finalize rsim row (|cos| vs relation rel)
//  C: score00/score01 + softmax (16-lane shuffle groups)
//  D: self rows + weighted neighbor gather -> xsT/xaT (transposed [d][row] layout)
//  E: fused matmul: 17 rows (16 hop-1 + 1 hop-0) x [128x128 Ws0 | Wn0]
//  F: combine 4 d-quarter partials in LDS
//  G: relu, aggregate v1 with w00 -> final matmul inputs
//  H: final matmul (v0@Ws1 + aggf@Wn1)
//  I: L2 normalize, write out
__global__ __launch_bounds__(256, 4) void gnn_kernel(
    const int* __restrict__ node, const int* __restrict__ relation,
    const int* __restrict__ adj_node, const int* __restrict__ adj_rela,
    const int* __restrict__ node_type, const float* __restrict__ node_emb,
    const float* __restrict__ rela_emb, const float* __restrict__ type_w,
    const float* __restrict__ Ws0, const float* __restrict__ Wn0,
    const float* __restrict__ Ws1, const float* __restrict__ Wn1,
    float* __restrict__ out)
{
    __shared__ __align__(16) float xsT[EMB * XST];   // [d][row] self inputs (rows 0..15 hop1, 16 hop0)
    __shared__ __align__(16) float xaT[EMB * XST];   // [d][row] agg inputs; reused as pb[17*128] later
    __shared__ __align__(16) float sw01[16][16];
    __shared__ float relv[EMB];
    __shared__ float sw00[16];
    __shared__ float srsim[16];
    __shared__ float sdij[16], sdrr[16];
    __shared__ float sagg[2][EMB];
    __shared__ __align__(16) int se2[16][16];
    __shared__ int se1[16], sr1[16], st1[16];
    __shared__ float sred[2];
    __shared__ float snorm;

    const int t = threadIdx.x;
    const int b = blockIdx.x;
    const int nb0 = node[b];
    const int rel = relation[b];

    // ---------- Phase A ----------
    if (t < 16) {
        int e1 = adj_node[nb0 * NB + t];
        se1[t] = e1;
        sr1[t] = adj_rela[nb0 * NB + t];
        st1[t] = node_type[e1];
    }
    if (t < EMB) relv[t] = rela_emb[rel * EMB + t];
    {
        // rsim row partials: 16 relations x 16 lanes each
        int r = t >> 4, c = t & 15;
        float dij = 0.f, drr = 0.f;
        #pragma unroll
        for (int dd = 0; dd < 8; ++dd) {
            int d = dd * 16 + c;
            float a  = rela_emb[rel * EMB + d];
            float bb = rela_emb[r * EMB + d];
            dij = fmaf(a, bb, dij);
            drr = fmaf(bb, bb, drr);
        }
        #pragma unroll
        for (int off = 8; off >= 1; off >>= 1) {
            dij += __shfl_xor(dij, off);
            drr += __shfl_xor(drr, off);
        }
        if (c == 0) { sdij[r] = dij; sdrr[r] = drr; }
    }
    __syncthreads();

    // ---------- Phase B ----------
    if (t < 16) {
        float nrel = fmaxf(sqrtf(sdrr[rel]), 1e-8f);
        float nr   = fmaxf(sqrtf(sdrr[t]),   1e-8f);
        srsim[t] = fabsf(sdij[t]) / (nr * nrel);
    }
    __syncthreads();

    // ---------- Phase C: scores ----------
    {
        int k = t >> 4, j = t & 15;
        int e1k = se1[k];
        int e2  = adj_node[e1k * NB + j];
        int r2  = adj_rela[e1k * NB + j];
        int t2  = node_type[e2];
        se2[k][j] = e2;
        float s = srsim[r2] * type_w[st1[k] * 4 + t2];
        float m = s;
        #pragma unroll
        for (int off = 8; off >= 1; off >>= 1) m = fmaxf(m, __shfl_xor(m, off));
        float ex = __expf(s - m);
        float sum = ex;
        #pragma unroll
        for (int off = 8; off >= 1; off >>= 1) sum += __shfl_xor(sum, off);
        sw01[k][j] = ex / sum;
    }
    {
        int t0type = node_type[nb0];
        if (t < 16) {
            float s = srsim[sr1[t]] * type_w[t0type * 4 + st1[t]];
            float m = s;
            #pragma unroll
            for (int off = 8; off >= 1; off >>= 1) m = fmaxf(m, __shfl_xor(m, off));
            float ex = __expf(s - m);
            float sum = ex;
            #pragma unroll
            for (int off = 8; off >= 1; off >>= 1) sum += __shfl_xor(sum, off);
            sw00[t] = ex / sum;
        }
    }
    __syncthreads();

    // ---------- Phase D: self rows + gather ----------
    {
        int e = t & 127, g = t >> 7;
        float rv = relv[e];
        float pagg0 = 0.f;
        for (int kk = 0; kk < 8; ++kk) {
            int k = g * 8 + kk;
            float selfv = node_emb[se1[k] * EMB + e];
            xsT[e * XST + k] = selfv * rv;
            pagg0 = fmaf(sw00[k], selfv, pagg0);

            int4 i0 = *(const int4*)&se2[k][0];
            int4 i1 = *(const int4*)&se2[k][4];
            int4 i2 = *(const int4*)&se2[k][8];
            int4 i3 = *(const int4*)&se2[k][12];
            float4 w0 = *(const float4*)&sw01[k][0];
            float4 w1 = *(const float4*)&sw01[k][4];
            float4 w2 = *(const float4*)&sw01[k][8];
            float4 w3 = *(const float4*)&sw01[k][12];
            float acc = 0.f;
            acc = fmaf(w0.x, node_emb[i0.x * EMB + e], acc);
            acc = fmaf(w0.y, node_emb[i0.y * EMB + e], acc);
            acc = fmaf(w0.z, node_emb[i0.z * EMB + e], acc);
            acc = fmaf(w0.w, node_emb[i0.w * EMB + e], acc);
            acc = fmaf(w1.x, node_emb[i1.x * EMB + e], acc);
            acc = fmaf(w1.y, node_emb[i1.y * EMB + e], acc);
            acc = fmaf(w1.z, node_emb[i1.z * EMB + e], acc);
            acc = fmaf(w1.w, node_emb[i1.w * EMB + e], acc);
            acc = fmaf(w2.x, node_emb[i2.x * EMB + e], acc);
            acc = fmaf(w2.y, node_emb[i2.y * EMB + e], acc);
            acc = fmaf(w2.z, node_emb[i2.z * EMB + e], acc);
            acc = fmaf(w2.w, node_emb[i2.w * EMB + e], acc);
            acc = fmaf(w3.x, node_emb[i3.x * EMB + e], acc);
            acc = fmaf(w3.y, node_emb[i3.y * EMB + e], acc);
            acc = fmaf(w3.z, node_emb[i3.z * EMB + e], acc);
            acc = fmaf(w3.w, node_emb[i3.w * EMB + e], acc);
            xaT[e * XST + k] = acc * rv;
        }
        sagg[g][e] = pagg0;
        if (g == 0) xsT[e * XST + 16] = node_emb[nb0 * EMB + e] * rv;  // ev0
    }
    __syncthreads();
    if (t < EMB) xaT[t * XST + 16] = (sagg[0][t] + sagg[1][t]) * relv[t];  // agg0
    __syncthreads();

    // ---------- Phase E: hop1 + hop0 matmul ----------
    const int l   = t & 63;
    const int h   = t >> 6;       // d-quarter
    const int e0  = l;
    const int e1c = l + 64;
    float acc[17][2];
    #pragma unroll
    for (int r = 0; r < 17; ++r) { acc[r][0] = 0.f; acc[r][1] = 0.f; }

    #pragma unroll 2
    for (int dd = 0; dd < 32; ++dd) {
        const int d = h * 32 + dd;
        const float* xsrow = &xsT[d * XST];
        const float* xarow = &xaT[d * XST];
        float xs[17], xa[17];
        float4 q;
        q = *(const float4*)(xsrow + 0);  xs[0]=q.x; xs[1]=q.y; xs[2]=q.z; xs[3]=q.w;
        q = *(const float4*)(xsrow + 4);  xs[4]=q.x; xs[5]=q.y; xs[6]=q.z; xs[7]=q.w;
        q = *(const float4*)(xsrow + 8);  xs[8]=q.x; xs[9]=q.y; xs[10]=q.z; xs[11]=q.w;
        q = *(const float4*)(xsrow + 12); xs[12]=q.x; xs[13]=q.y; xs[14]=q.z; xs[15]=q.w;
        xs[16] = xsrow[16];
        q = *(const float4*)(xarow + 0);  xa[0]=q.x; xa[1]=q.y; xa[2]=q.z; xa[3]=q.w;
        q = *(const float4*)(xarow + 4);  xa[4]=q.x; xa[5]=q.y; xa[6]=q.z; xa[7]=q.w;
        q = *(const float4*)(xarow + 8);  xa[8]=q.x; xa[9]=q.y; xa[10]=q.z; xa[11]=q.w;
        q = *(const float4*)(xarow + 12); xa[12]=q.x; xa[13]=q.y; xa[14]=q.z; xa[15]=q.w;
        xa[16] = xarow[16];

        const float wA0 = Ws0[d * EMB + e0];
        const float wA1 = Ws0[d * EMB + e1c];
        const float wB0 = Wn0[d * EMB + e0];
        const float wB1 = Wn0[d * EMB + e1c];
        #pragma unroll
        for (int r = 0; r < 17; ++r) {
            acc[r][0] = fmaf(xs[r], wA0, acc[r][0]);
            acc[r][0] = fmaf(xa[r], wB0, acc[r][0]);
            acc[r][1] = fmaf(xs[r], wA1, acc[r][1]);
            acc[r][1] = fmaf(xa[r], wB1, acc[r][1]);
        }
    }
    __syncthreads();

    // ---------- Phase F: combine d-quarter partials ----------
    float* pb = xaT;  // 17*128 = 2176 floats fits in xaT's 2560
    for (int hh = 0; hh < 4; ++hh) {
        if (h == hh) {
            #pragma unroll
            for (int r = 0; r < 17; ++r) {
                if (hh == 0) {
                    pb[r * 128 + e0]  = acc[r][0];
                    pb[r * 128 + e1c] = acc[r][1];
                } else {
                    pb[r * 128 + e0]  += acc[r][0];
                    pb[r * 128 + e1c] += acc[r][1];
                }
            }
        }
        __syncthreads();
    }

    // ---------- Phase G: relu + final inputs ----------
    if (t < EMB) {
        int e = t;
        float v0 = fmaxf(pb[16 * 128 + e], 0.f);
        float aggf = 0.f;
        #pragma unroll
        for (int k = 0; k < 16; ++k)
            aggf = fmaf(sw00[k], fmaxf(pb[k * 128 + e], 0.f), aggf);
        xsT[e * XST + 0] = v0;
        xsT[e * XST + 1] = aggf;
    }
    __syncthreads();

    // ---------- Phase H: final matmul ----------
    float a2_0 = 0.f, a2_1 = 0.f;
    for (int dd = 0; dd < 32; ++dd) {
        const int d = h * 32 + dd;
        float xf0 = xsT[d * XST + 0];
        float xf1 = xsT[d * XST + 1];
        a2_0 = fmaf(xf0, Ws1[d * EMB + e0],  fmaf(xf1, Wn1[d * EMB + e0],  a2_0));
        a2_1 = fmaf(xf0, Ws1[d * EMB + e1c], fmaf(xf1, Wn1[d * EMB + e1c], a2_1));
    }
    pb[h * 128 + e0]  = a2_0;   // rows 0..3: per-quarter partials (reads of pb all done in G)
    pb[h * 128 + e1c] = a2_1;
    __syncthreads();

    // ---------- Phase I: L2 normalize ----------
    if (t < EMB) {
        float o = pb[0 * 128 + t] + pb[1 * 128 + t] + pb[2 * 128 + t] + pb[3 * 128 + t];
        float sq = o * o;
        #pragma unroll
        for (int off = 1; off < 64; off <<= 1) sq += __shfl_xor(sq, off);
        if ((t & 63) == 0) sred[t >> 6] = sq;
    }
    __syncthreads();
    if (t == 0) snorm = 1.f / fmaxf(sqrtf(sred[0] + sred[1]), 1e-12f);
    __syncthreads();
    if (t < EMB) {
        float o = pb[0 * 128 + t] + pb[1 * 128 + t] + pb[2 * 128 + t] + pb[3 * 128 + t];
        out[b * EMB + t] = o * snorm;
    }
}

extern "C" void kernel_launch(void* const* d_in, const int* in_sizes, int n_in,
                              void* d_out, int out_size, void* d_ws, size_t ws_size,
                              hipStream_t stream) {
    (void)n_in; (void)out_size; (void)d_ws; (void)ws_size;
    const int*   node      = (const int*)d_in[0];
    const int*   relation  = (const int*)d_in[1];
    const int*   adj_node  = (const int*)d_in[2];
    const int*   adj_rela  = (const int*)d_in[3];
    const int*   node_type = (const int*)d_in[4];
    const float* node_emb  = (const float*)d_in[5];
    const float* rela_emb  = (const float*)d_in[6];
    const float* type_w    = (const float*)d_in[7];
    const float* Ws0       = (const float*)d_in[8];
    const float* Wn0       = (const float*)d_in[9];
    const float* Ws1       = (const float*)d_in[10];
    const float* Wn1       = (const float*)d_in[11];
    float* out = (float*)d_out;
    const int B = in_sizes[0];

    gnn_kernel<<<B, 256, 0, stream>>>(node, relation, adj_node, adj_rela, node_type,
                                      node_emb, rela_emb, type_w, Ws0, Wn0, Ws1, Wn1, out);
}

// Round 2
// 112.235 us; speedup vs baseline: 1.3959x; 1.3959x over previous
//
#include <hip/hip_runtime.h>
#include <math.h>

#define NB   16
#define EMB  128

typedef __bf16 bf16x8 __attribute__((ext_vector_type(8)));
typedef float  f32x4  __attribute__((ext_vector_type(4)));

// ---------------------------------------------------------------------------
// Prep: pack [Ws0; Wn0] (K=256 x N=128) as bf16 MFMA B-fragments.
// Layout: frag (s,nt) at pack[((s*8+nt)*64 + lane)*8 + j], holding
// W[k = s*32 + (lane>>4)*8 + j][col = nt*16 + (lane&15)].
// Per-wave B-frag load is then one coalesced 16B/lane global read.
// ---------------------------------------------------------------------------
__global__ __launch_bounds__(256) void pack_w_kernel(
    const float* __restrict__ Ws0, const float* __restrict__ Wn0,
    __bf16* __restrict__ pack)
{
    int idx = blockIdx.x * 256 + threadIdx.x;   // (s<<9)|(nt<<6)|lane
    if (idx >= 4096) return;
    int l  = idx & 63;
    int nt = (idx >> 6) & 7;
    int s  = idx >> 9;
    int col = nt * 16 + (l & 15);
    int k0  = s * 32 + (l >> 4) * 8;
    bf16x8 v;
    #pragma unroll
    for (int j = 0; j < 8; ++j) {
        int k = k0 + j;
        float wv = (k < 128) ? Ws0[k * EMB + col] : Wn0[(k - 128) * EMB + col];
        v[j] = (__bf16)wv;
    }
    *(bf16x8*)(pack + idx * 8) = v;
}

// ---------------------------------------------------------------------------
// Main fused kernel: one block (256 thr = 4 waves) per batch element.
//  A: e1/r1/t1, rel_vec, rsim partial dots
//  B: rsim row |cos|
//  C: score00/score01 softmax (16-lane shuffle groups)
//  D: self rows + weighted gather -> X (17 x 256 bf16, row-major, XOR-swizzled)
//  E: MFMA  P = X @ [Ws0;Wn0]  (2 M-tiles x 8 N-tiles x 8 K-steps)
//  F: in-register relu + w00-weighted agg from acc frags -> fv0 / fagg (LDS)
//  H: final fp32 matmul  out = v0@Ws1 + aggf@Wn1 (per-quarter partials)
//  I: L2 normalize
// ---------------------------------------------------------------------------
__global__ __launch_bounds__(256, 4) void gnn_kernel(
    const int* __restrict__ node, const int* __restrict__ relation,
    const int* __restrict__ adj_node, const int* __restrict__ adj_rela,
    const int* __restrict__ node_type, const float* __restrict__ node_emb,
    const float* __restrict__ rela_emb, const float* __restrict__ type_w,
    const float* __restrict__ Ws1, const float* __restrict__ Wn1,
    const __bf16* __restrict__ packW0,
    float* __restrict__ out)
{
    // X: row r in [0,17), col c in [0,256): byte = (r*512 + c*2) ^ ((r&7)<<4)
    __shared__ __align__(16) unsigned char Xb[17 * 512];
    __shared__ __align__(16) float sw01[16][16];
    __shared__ __align__(16) int   se2[16][16];
    __shared__ float relv[EMB];
    __shared__ float sagg[2][EMB];
    __shared__ float fv0[EMB];     // v0 = relu(hop0 row of P)
    __shared__ float fagg[EMB];    // sum_k w00[k]*relu(P[k])
    __shared__ float pb[4][EMB];   // final-matmul per-quarter partials
    __shared__ float sw00[16];
    __shared__ float srsim[16];
    __shared__ float sdij[16], sdrr[16];
    __shared__ int   se1[16], sr1[16], st1[16];
    __shared__ float sred[2];
    __shared__ float snorm;

    const int t   = threadIdx.x;
    const int b   = blockIdx.x;
    const int nb0 = node[b];
    const int rel = relation[b];

    // ---------- Phase A ----------
    if (t < 16) {
        int e1 = adj_node[nb0 * NB + t];
        se1[t] = e1;
        sr1[t] = adj_rela[nb0 * NB + t];
        st1[t] = node_type[e1];
    }
    if (t < EMB) relv[t] = rela_emb[rel * EMB + t];
    {
        int r = t >> 4, c = t & 15;
        float dij = 0.f, drr = 0.f;
        #pragma unroll
        for (int dd = 0; dd < 8; ++dd) {
            int d = dd * 16 + c;
            float a  = rela_emb[rel * EMB + d];
            float bb = rela_emb[r * EMB + d];
            dij = fmaf(a, bb, dij);
            drr = fmaf(bb, bb, drr);
        }
        #pragma unroll
        for (int off = 8; off >= 1; off >>= 1) {
            dij += __shfl_xor(dij, off);
            drr += __shfl_xor(drr, off);
        }
        if (c == 0) { sdij[r] = dij; sdrr[r] = drr; }
    }
    __syncthreads();

    // ---------- Phase B ----------
    if (t < 16) {
        float nrel = fmaxf(sqrtf(sdrr[rel]), 1e-8f);
        float nr   = fmaxf(sqrtf(sdrr[t]),   1e-8f);
        srsim[t] = fabsf(sdij[t]) / (nr * nrel);
    }
    __syncthreads();

    // ---------- Phase C: scores + softmax ----------
    {
        int k = t >> 4, j = t & 15;
        int e1k = se1[k];
        int e2  = adj_node[e1k * NB + j];
        int r2  = adj_rela[e1k * NB + j];
        int t2  = node_type[e2];
        se2[k][j] = e2;
        float s = srsim[r2] * type_w[st1[k] * 4 + t2];
        float m = s;
        #pragma unroll
        for (int off = 8; off >= 1; off >>= 1) m = fmaxf(m, __shfl_xor(m, off));
        float ex = __expf(s - m);
        float sum = ex;
        #pragma unroll
        for (int off = 8; off >= 1; off >>= 1) sum += __shfl_xor(sum, off);
        sw01[k][j] = ex / sum;
    }
    {
        int t0type = node_type[nb0];
        if (t < 16) {
            float s = srsim[sr1[t]] * type_w[t0type * 4 + st1[t]];
            float m = s;
            #pragma unroll
            for (int off = 8; off >= 1; off >>= 1) m = fmaxf(m, __shfl_xor(m, off));
            float ex = __expf(s - m);
            float sum = ex;
            #pragma unroll
            for (int off = 8; off >= 1; off >>= 1) sum += __shfl_xor(sum, off);
            sw00[t] = ex / sum;
        }
    }
    __syncthreads();

    // ---------- Phase D: self rows + weighted gather -> X (bf16) ----------
    {
        int e = t & 127, g = t >> 7;
        float rv = relv[e];
        float pagg0 = 0.f;
        for (int kk = 0; kk < 8; ++kk) {
            int k = g * 8 + kk;
            float selfv = node_emb[se1[k] * EMB + e];
            *(__bf16*)(Xb + ((k * 512 + e * 2) ^ ((k & 7) << 4))) = (__bf16)(selfv * rv);
            pagg0 = fmaf(sw00[k], selfv, pagg0);

            int4 i0 = *(const int4*)&se2[k][0];
            int4 i1 = *(const int4*)&se2[k][4];
            int4 i2 = *(const int4*)&se2[k][8];
            int4 i3 = *(const int4*)&se2[k][12];
            float4 w0 = *(const float4*)&sw01[k][0];
            float4 w1 = *(const float4*)&sw01[k][4];
            float4 w2 = *(const float4*)&sw01[k][8];
            float4 w3 = *(const float4*)&sw01[k][12];
            float acc = 0.f;
            acc = fmaf(w0.x, node_emb[i0.x * EMB + e], acc);
            acc = fmaf(w0.y, node_emb[i0.y * EMB + e], acc);
            acc = fmaf(w0.z, node_emb[i0.z * EMB + e], acc);
            acc = fmaf(w0.w, node_emb[i0.w * EMB + e], acc);
            acc = fmaf(w1.x, node_emb[i1.x * EMB + e], acc);
            acc = fmaf(w1.y, node_emb[i1.y * EMB + e], acc);
            acc = fmaf(w1.z, node_emb[i1.z * EMB + e], acc);
            acc = fmaf(w1.w, node_emb[i1.w * EMB + e], acc);
            acc = fmaf(w2.x, node_emb[i2.x * EMB + e], acc);
            acc = fmaf(w2.y, node_emb[i2.y * EMB + e], acc);
            acc = fmaf(w2.z, node_emb[i2.z * EMB + e], acc);
            acc = fmaf(w2.w, node_emb[i2.w * EMB + e], acc);
            acc = fmaf(w3.x, node_emb[i3.x * EMB + e], acc);
            acc = fmaf(w3.y, node_emb[i3.y * EMB + e], acc);
            acc = fmaf(w3.z, node_emb[i3.z * EMB + e], acc);
            acc = fmaf(w3.w, node_emb[i3.w * EMB + e], acc);
            *(__bf16*)(Xb + ((k * 512 + (128 + e) * 2) ^ ((k & 7) << 4))) = (__bf16)(acc * rv);
        }
        sagg[g][e] = pagg0;
        if (g == 0)  // hop-0 self row (row 16, (16&7)<<4 == 0 -> no swizzle)
            *(__bf16*)(Xb + 16 * 512 + e * 2) = (__bf16)(node_emb[nb0 * EMB + e] * rv);
    }
    __syncthreads();
    if (t < EMB)
        *(__bf16*)(Xb + 16 * 512 + (128 + t) * 2) = (__bf16)((sagg[0][t] + sagg[1][t]) * relv[t]);
    __syncthreads();

    // ---------- Phase E: MFMA  P = X @ [Ws0;Wn0] ----------
    const int w = t >> 6, l = t & 63;
    f32x4 acc00 = {0.f, 0.f, 0.f, 0.f};
    f32x4 acc01 = {0.f, 0.f, 0.f, 0.f};
    f32x4 acc10 = {0.f, 0.f, 0.f, 0.f};
    f32x4 acc11 = {0.f, 0.f, 0.f, 0.f};
    {
        const int row0 = l & 15;
        const int kb   = (l >> 4) * 16;             // byte offset of k-subblock
        const int sw0  = (row0 & 7) << 4;
        #pragma unroll
        for (int s = 0; s < 8; ++s) {
            bf16x8 a0 = *(const bf16x8*)(Xb + ((row0 * 512 + s * 64 + kb) ^ sw0));
            bf16x8 a1 = *(const bf16x8*)(Xb + (16 * 512 + s * 64 + kb));   // broadcast hop-0 row
            bf16x8 b0 = *(const bf16x8*)(packW0 + (((s * 8 + 2 * w) * 64 + l) * 8));
            bf16x8 b1 = *(const bf16x8*)(packW0 + (((s * 8 + 2 * w + 1) * 64 + l) * 8));
            acc00 = __builtin_amdgcn_mfma_f32_16x16x32_bf16(a0, b0, acc00, 0, 0, 0);
            acc01 = __builtin_amdgcn_mfma_f32_16x16x32_bf16(a0, b1, acc01, 0, 0, 0);
            acc10 = __builtin_amdgcn_mfma_f32_16x16x32_bf16(a1, b0, acc10, 0, 0, 0);
            acc11 = __builtin_amdgcn_mfma_f32_16x16x32_bf16(a1, b1, acc11, 0, 0, 0);
        }
    }

    // ---------- Phase F: in-register relu + weighted agg ----------
    {
        const int rbase = (l >> 4) * 4;   // D rows = rbase..rbase+3, col = l&15
        float s0 = 0.f, s1 = 0.f;
        #pragma unroll
        for (int r = 0; r < 4; ++r) {
            float wk = sw00[rbase + r];
            s0 = fmaf(wk, fmaxf(acc00[r], 0.f), s0);
            s1 = fmaf(wk, fmaxf(acc01[r], 0.f), s1);
        }
        s0 += __shfl_xor(s0, 16); s0 += __shfl_xor(s0, 32);
        s1 += __shfl_xor(s1, 16); s1 += __shfl_xor(s1, 32);
        if (l < 16) {
            int c0 = (2 * w) * 16 + l, c1 = (2 * w + 1) * 16 + l;
            fagg[c0] = s0;
            fagg[c1] = s1;
            fv0[c0]  = fmaxf(acc10[0], 0.f);   // reg0 = broadcast hop-0 row
            fv0[c1]  = fmaxf(acc11[0], 0.f);
        }
    }
    __syncthreads();

    // ---------- Phase H: final fp32 matmul ----------
    {
        const int h = w;   // d-quarter
        float a2_0 = 0.f, a2_1 = 0.f;
        for (int dd = 0; dd < 32; ++dd) {
            const int d = h * 32 + dd;
            float xf0 = fv0[d];
            float xf1 = fagg[d];
            a2_0 = fmaf(xf0, Ws1[d * EMB + l],      fmaf(xf1, Wn1[d * EMB + l],      a2_0));
            a2_1 = fmaf(xf0, Ws1[d * EMB + l + 64], fmaf(xf1, Wn1[d * EMB + l + 64], a2_1));
        }
        pb[h][l]      = a2_0;
        pb[h][l + 64] = a2_1;
    }
    __syncthreads();

    // ---------- Phase I: L2 normalize ----------
    if (t < EMB) {
        float o = pb[0][t] + pb[1][t] + pb[2][t] + pb[3][t];
        float sq = o * o;
        #pragma unroll
        for (int off = 1; off < 64; off <<= 1) sq += __shfl_xor(sq, off);
        if ((t & 63) == 0) sred[t >> 6] = sq;
    }
    __syncthreads();
    if (t == 0) snorm = 1.f / fmaxf(sqrtf(sred[0] + sred[1]), 1e-12f);
    __syncthreads();
    if (t < EMB) {
        float o = pb[0][t] + pb[1][t] + pb[2][t] + pb[3][t];
        out[b * EMB + t] = o * snorm;
    }
}

extern "C" void kernel_launch(void* const* d_in, const int* in_sizes, int n_in,
                              void* d_out, int out_size, void* d_ws, size_t ws_size,
                              hipStream_t stream) {
    (void)n_in; (void)out_size; (void)ws_size;
    const int*   node      = (const int*)d_in[0];
    const int*   relation  = (const int*)d_in[1];
    const int*   adj_node  = (const int*)d_in[2];
    const int*   adj_rela  = (const int*)d_in[3];
    const int*   node_type = (const int*)d_in[4];
    const float* node_emb  = (const float*)d_in[5];
    const float* rela_emb  = (const float*)d_in[6];
    const float* type_w    = (const float*)d_in[7];
    const float* Ws0       = (const float*)d_in[8];
    const float* Wn0       = (const float*)d_in[9];
    const float* Ws1       = (const float*)d_in[10];
    const float* Wn1       = (const float*)d_in[11];
    float* out = (float*)d_out;
    const int B = in_sizes[0];

    __bf16* packW0 = (__bf16*)d_ws;   // 4096 frags * 8 bf16 = 64 KB

    pack_w_kernel<<<16, 256, 0, stream>>>(Ws0, Wn0, packW0);
    gnn_kernel<<<B, 256, 0, stream>>>(node, relation, adj_node, adj_rela, node_type,
                                      node_emb, rela_emb, type_w, Ws1, Wn1, packW0, out);
}

// Round 3
// 107.639 us; speedup vs baseline: 1.4555x; 1.0427x over previous
//
#include <hip/hip_runtime.h>
#include <math.h>

#define NB   16
#define EMB  128

typedef __bf16 bf16x8 __attribute__((ext_vector_type(8)));
typedef __bf16 bf16x4 __attribute__((ext_vector_type(4)));
typedef float  f32x4  __attribute__((ext_vector_type(4)));
typedef int    i32x4  __attribute__((ext_vector_type(4)));

// ---------------------------------------------------------------------------
// Prep: pack [Ws0; Wn0] (K=256 x N=128) as bf16 MFMA B-fragments.
// frag (s,nt) at pack[((s*8+nt)*64 + lane)*8 + j] holds
// W[k = s*32 + (lane>>4)*8 + j][col = nt*16 + (lane&15)].
// ---------------------------------------------------------------------------
__global__ __launch_bounds__(256) void pack_w_kernel(
    const float* __restrict__ Ws0, const float* __restrict__ Wn0,
    __bf16* __restrict__ pack)
{
    int idx = blockIdx.x * 256 + threadIdx.x;   // (s<<9)|(nt<<6)|lane
    if (idx >= 4096) return;
    int l  = idx & 63;
    int nt = (idx >> 6) & 7;
    int s  = idx >> 9;
    int col = nt * 16 + (l & 15);
    int k0  = s * 32 + (l >> 4) * 8;
    bf16x8 v;
    #pragma unroll
    for (int j = 0; j < 8; ++j) {
        int k = k0 + j;
        float wv = (k < 128) ? Ws0[k * EMB + col] : Wn0[(k - 128) * EMB + col];
        v[j] = (__bf16)wv;
    }
    *(bf16x8*)(pack + idx * 8) = v;
}

// ---------------------------------------------------------------------------
// Main fused kernel: one block (256 thr = 4 waves) per batch element.
//  A: e1/r1/t1, rel_vec, rsim partial dots
//  B: rsim row |cos|
//  C: score00/score01 softmax (16-lane shuffle groups)
//  D: float4 gather: thread=(quad q, group g), k in {g, g+8}; 1KB/wave-instr
//  E: MFMA  P = X @ [Ws0;Wn0]  (X: 17x256 bf16 rows, XOR-swizzled)
//  F: in-register relu + w00-weighted agg -> y0/y1 (f32 LDS)
//  H: float4 fp32 final matmul, [8][32] partial reduce
//  I: L2 normalize (32 lanes, float4)
// ---------------------------------------------------------------------------
__global__ __launch_bounds__(256, 4) void gnn_kernel(
    const int* __restrict__ node, const int* __restrict__ relation,
    const int* __restrict__ adj_node, const int* __restrict__ adj_rela,
    const int* __restrict__ node_type, const float* __restrict__ node_emb,
    const float* __restrict__ rela_emb, const float* __restrict__ type_w,
    const float* __restrict__ Ws1, const float* __restrict__ Wn1,
    const __bf16* __restrict__ packW0,
    float* __restrict__ out)
{
    // X: row r in [0,17), col c in [0,256): byte = (r*512 + c*2) ^ ((r&7)<<4)
    __shared__ __align__(16) unsigned char Xb[17 * 512];
    __shared__ __align__(16) float sw01[16][16];
    __shared__ __align__(16) int   se2[16][16];
    __shared__ __align__(16) float relv[EMB];
    __shared__ __align__(16) f32x4 red4[8][32];   // D: agg0 partials; H: out partials
    __shared__ __align__(16) float y0[EMB];       // v0
    __shared__ __align__(16) float y1[EMB];       // aggf
    __shared__ float sw00[16];
    __shared__ float srsim[16];
    __shared__ float sdij[16], sdrr[16];
    __shared__ int   se1[16], sr1[16], st1[16];

    const int t   = threadIdx.x;
    const int b   = blockIdx.x;
    const int nb0 = node[b];
    const int rel = relation[b];

    // ---------- Phase A ----------
    if (t < 16) {
        int e1 = adj_node[nb0 * NB + t];
        se1[t] = e1;
        sr1[t] = adj_rela[nb0 * NB + t];
        st1[t] = node_type[e1];
    }
    if (t < EMB) relv[t] = rela_emb[rel * EMB + t];
    {
        int r = t >> 4, c = t & 15;
        float dij = 0.f, drr = 0.f;
        #pragma unroll
        for (int dd = 0; dd < 8; ++dd) {
            int d = dd * 16 + c;
            float a  = rela_emb[rel * EMB + d];
            float bb = rela_emb[r * EMB + d];
            dij = fmaf(a, bb, dij);
            drr = fmaf(bb, bb, drr);
        }
        #pragma unroll
        for (int off = 8; off >= 1; off >>= 1) {
            dij += __shfl_xor(dij, off);
            drr += __shfl_xor(drr, off);
        }
        if (c == 0) { sdij[r] = dij; sdrr[r] = drr; }
    }
    __syncthreads();

    // ---------- Phase B ----------
    if (t < 16) {
        float nrel = fmaxf(sqrtf(sdrr[rel]), 1e-8f);
        float nr   = fmaxf(sqrtf(sdrr[t]),   1e-8f);
        srsim[t] = fabsf(sdij[t]) / (nr * nrel);
    }
    __syncthreads();

    // ---------- Phase C: scores + softmax ----------
    {
        int k = t >> 4, j = t & 15;
        int e1k = se1[k];
        int e2  = adj_node[e1k * NB + j];
        int r2  = adj_rela[e1k * NB + j];
        int t2  = node_type[e2];
        se2[k][j] = e2;
        float s = srsim[r2] * type_w[st1[k] * 4 + t2];
        float m = s;
        #pragma unroll
        for (int off = 8; off >= 1; off >>= 1) m = fmaxf(m, __shfl_xor(m, off));
        float ex = __expf(s - m);
        float sum = ex;
        #pragma unroll
        for (int off = 8; off >= 1; off >>= 1) sum += __shfl_xor(sum, off);
        sw01[k][j] = ex / sum;
    }
    {
        int t0type = node_type[nb0];
        if (t < 16) {
            float s = srsim[sr1[t]] * type_w[t0type * 4 + st1[t]];
            float m = s;
            #pragma unroll
            for (int off = 8; off >= 1; off >>= 1) m = fmaxf(m, __shfl_xor(m, off));
            float ex = __expf(s - m);
            float sum = ex;
            #pragma unroll
            for (int off = 8; off >= 1; off >>= 1) sum += __shfl_xor(sum, off);
            sw00[t] = ex / sum;
        }
    }
    __syncthreads();

    // ---------- Phase D: float4 gather -> X rows ----------
    {
        const int q = t & 31;     // col quad: cols 4q..4q+3
        const int g = t >> 5;     // 0..7 -> k in {g, g+8}
        const float* __restrict__ nbq = node_emb + q * 4;
        const f32x4 rv4 = *(const f32x4*)&relv[q * 4];
        f32x4 pagg = {0.f, 0.f, 0.f, 0.f};

        for (int kx = 0; kx < 2; ++kx) {
            const int k = g + kx * 8;
            const int swz = (k & 7) << 4;

            // self row
            const f32x4 sv = *(const f32x4*)(nbq + (se1[k] << 7));
            const float wk0 = sw00[k];
            pagg += wk0 * sv;
            bf16x4 xs;
            xs[0] = (__bf16)(sv[0] * rv4[0]);
            xs[1] = (__bf16)(sv[1] * rv4[1]);
            xs[2] = (__bf16)(sv[2] * rv4[2]);
            xs[3] = (__bf16)(sv[3] * rv4[3]);
            *(bf16x4*)(Xb + ((k * 512 + q * 8) ^ swz)) = xs;

            // neighbor indices + weights (broadcast ds_read_b128)
            i32x4 i0 = *(const i32x4*)&se2[k][0];
            i32x4 i1 = *(const i32x4*)&se2[k][4];
            i32x4 i2 = *(const i32x4*)&se2[k][8];
            i32x4 i3 = *(const i32x4*)&se2[k][12];
            f32x4 w0 = *(const f32x4*)&sw01[k][0];
            f32x4 w1 = *(const f32x4*)&sw01[k][4];
            f32x4 w2 = *(const f32x4*)&sw01[k][8];
            f32x4 w3 = *(const f32x4*)&sw01[k][12];

            // issue all 16 row loads, then combine
            f32x4 v0  = *(const f32x4*)(nbq + (i0[0] << 7));
            f32x4 v1  = *(const f32x4*)(nbq + (i0[1] << 7));
            f32x4 v2  = *(const f32x4*)(nbq + (i0[2] << 7));
            f32x4 v3  = *(const f32x4*)(nbq + (i0[3] << 7));
            f32x4 v4  = *(const f32x4*)(nbq + (i1[0] << 7));
            f32x4 v5  = *(const f32x4*)(nbq + (i1[1] << 7));
            f32x4 v6  = *(const f32x4*)(nbq + (i1[2] << 7));
            f32x4 v7  = *(const f32x4*)(nbq + (i1[3] << 7));
            f32x4 v8  = *(const f32x4*)(nbq + (i2[0] << 7));
            f32x4 v9  = *(const f32x4*)(nbq + (i2[1] << 7));
            f32x4 v10 = *(const f32x4*)(nbq + (i2[2] << 7));
            f32x4 v11 = *(const f32x4*)(nbq + (i2[3] << 7));
            f32x4 v12 = *(const f32x4*)(nbq + (i3[0] << 7));
            f32x4 v13 = *(const f32x4*)(nbq + (i3[1] << 7));
            f32x4 v14 = *(const f32x4*)(nbq + (i3[2] << 7));
            f32x4 v15 = *(const f32x4*)(nbq + (i3[3] << 7));

            f32x4 acc = w0[0] * v0;
            acc += w0[1] * v1;
            acc += w0[2] * v2;
            acc += w0[3] * v3;
            acc += w1[0] * v4;
            acc += w1[1] * v5;
            acc += w1[2] * v6;
            acc += w1[3] * v7;
            acc += w2[0] * v8;
            acc += w2[1] * v9;
            acc += w2[2] * v10;
            acc += w2[3] * v11;
            acc += w3[0] * v12;
            acc += w3[1] * v13;
            acc += w3[2] * v14;
            acc += w3[3] * v15;

            bf16x4 xa;
            xa[0] = (__bf16)(acc[0] * rv4[0]);
            xa[1] = (__bf16)(acc[1] * rv4[1]);
            xa[2] = (__bf16)(acc[2] * rv4[2]);
            xa[3] = (__bf16)(acc[3] * rv4[3]);
            *(bf16x4*)(Xb + ((k * 512 + 256 + q * 8) ^ swz)) = xa;
        }
        red4[g][q] = pagg;
    }
    __syncthreads();
    if (t < 32) {
        f32x4 s = red4[0][t];
        #pragma unroll
        for (int g = 1; g < 8; ++g) s += red4[g][t];
        const f32x4 rv4 = *(const f32x4*)&relv[t * 4];
        const f32x4 ev0 = *(const f32x4*)(node_emb + (nb0 << 7) + t * 4);
        bf16x4 h0s, h0a;
        #pragma unroll
        for (int c = 0; c < 4; ++c) {
            h0s[c] = (__bf16)(ev0[c] * rv4[c]);
            h0a[c] = (__bf16)(s[c]   * rv4[c]);
        }
        *(bf16x4*)(Xb + 16 * 512 + t * 8)       = h0s;   // row16 (no swizzle)
        *(bf16x4*)(Xb + 16 * 512 + 256 + t * 8) = h0a;
    }
    __syncthreads();

    // ---------- Phase E: MFMA  P = X @ [Ws0;Wn0] ----------
    const int w = t >> 6, l = t & 63;
    f32x4 acc00 = {0.f, 0.f, 0.f, 0.f};
    f32x4 acc01 = {0.f, 0.f, 0.f, 0.f};
    f32x4 acc10 = {0.f, 0.f, 0.f, 0.f};
    f32x4 acc11 = {0.f, 0.f, 0.f, 0.f};
    {
        const int row0 = l & 15;
        const int kb   = (l >> 4) * 16;
        const int sw0  = (row0 & 7) << 4;
        #pragma unroll
        for (int s = 0; s < 8; ++s) {
            bf16x8 a0 = *(const bf16x8*)(Xb + ((row0 * 512 + s * 64 + kb) ^ sw0));
            bf16x8 a1 = *(const bf16x8*)(Xb + (16 * 512 + s * 64 + kb));
            bf16x8 b0 = *(const bf16x8*)(packW0 + (((s * 8 + 2 * w) * 64 + l) * 8));
            bf16x8 b1 = *(const bf16x8*)(packW0 + (((s * 8 + 2 * w + 1) * 64 + l) * 8));
            acc00 = __builtin_amdgcn_mfma_f32_16x16x32_bf16(a0, b0, acc00, 0, 0, 0);
            acc01 = __builtin_amdgcn_mfma_f32_16x16x32_bf16(a0, b1, acc01, 0, 0, 0);
            acc10 = __builtin_amdgcn_mfma_f32_16x16x32_bf16(a1, b0, acc10, 0, 0, 0);
            acc11 = __builtin_amdgcn_mfma_f32_16x16x32_bf16(a1, b1, acc11, 0, 0, 0);
        }
    }

    // ---------- Phase F: in-register relu + weighted agg ----------
    {
        const int rbase = (l >> 4) * 4;
        float s0 = 0.f, s1 = 0.f;
        #pragma unroll
        for (int r = 0; r < 4; ++r) {
            float wk = sw00[rbase + r];
            s0 = fmaf(wk, fmaxf(acc00[r], 0.f), s0);
            s1 = fmaf(wk, fmaxf(acc01[r], 0.f), s1);
        }
        s0 += __shfl_xor(s0, 16); s0 += __shfl_xor(s0, 32);
        s1 += __shfl_xor(s1, 16); s1 += __shfl_xor(s1, 32);
        if (l < 16) {
            int c0 = (2 * w) * 16 + l, c1 = (2 * w + 1) * 16 + l;
            y1[c0] = s0;
            y1[c1] = s1;
            y0[c0] = fmaxf(acc10[0], 0.f);
            y0[c1] = fmaxf(acc11[0], 0.f);
        }
    }
    __syncthreads();

    // ---------- Phase H: float4 fp32 final matmul ----------
    {
        const int q = t & 31;
        const int g = t >> 5;
        const int d0 = g * 16;
        f32x4 a = {0.f, 0.f, 0.f, 0.f};
        #pragma unroll
        for (int dq = 0; dq < 4; ++dq) {
            f32x4 ys = *(const f32x4*)&y0[d0 + dq * 4];
            f32x4 ya = *(const f32x4*)&y1[d0 + dq * 4];
            #pragma unroll
            for (int jj = 0; jj < 4; ++jj) {
                const int d = d0 + dq * 4 + jj;
                f32x4 ws = *(const f32x4*)(Ws1 + d * EMB + q * 4);
                f32x4 wn = *(const f32x4*)(Wn1 + d * EMB + q * 4);
                a += ys[jj] * ws;
                a += ya[jj] * wn;
            }
        }
        red4[g][q] = a;
    }
    __syncthreads();

    // ---------- Phase I: L2 normalize + write ----------
    if (t < 32) {
        f32x4 o = red4[0][t];
        #pragma unroll
        for (int g = 1; g < 8; ++g) o += red4[g][t];
        float sq = o[0] * o[0] + o[1] * o[1] + o[2] * o[2] + o[3] * o[3];
        #pragma unroll
        for (int off = 1; off < 32; off <<= 1) sq += __shfl_xor(sq, off);
        float inv = 1.f / fmaxf(sqrtf(sq), 1e-12f);
        o *= inv;
        *(f32x4*)(out + b * EMB + t * 4) = o;
    }
}

extern "C" void kernel_launch(void* const* d_in, const int* in_sizes, int n_in,
                              void* d_out, int out_size, void* d_ws, size_t ws_size,
                              hipStream_t stream) {
    (void)n_in; (void)out_size; (void)ws_size;
    const int*   node      = (const int*)d_in[0];
    const int*   relation  = (const int*)d_in[1];
    const int*   adj_node  = (const int*)d_in[2];
    const int*   adj_rela  = (const int*)d_in[3];
    const int*   node_type = (const int*)d_in[4];
    const float* node_emb  = (const float*)d_in[5];
    const float* rela_emb  = (const float*)d_in[6];
    const float* type_w    = (const float*)d_in[7];
    const float* Ws0       = (const float*)d_in[8];
    const float* Wn0       = (const float*)d_in[9];
    const float* Ws1       = (const float*)d_in[10];
    const float* Wn1       = (const float*)d_in[11];
    float* out = (float*)d_out;
    const int B = in_sizes[0];

    __bf16* packW0 = (__bf16*)d_ws;   // 4096 frags * 8 bf16 = 64 KB

    pack_w_kernel<<<16, 256, 0, stream>>>(Ws0, Wn0, packW0);
    gnn_kernel<<<B, 256, 0, stream>>>(node, relation, adj_node, adj_rela, node_type,
                                      node_emb, rela_emb, type_w, Ws1, Wn1, packW0, out);
}